// Round 8
// baseline (232.529 us; speedup 1.0000x reference)
//
#include <hip/hip_runtime.h>

// DynamicConvolution fused pipeline for MI355X (gfx950).
// R8: kFA re-tiled for occupancy — q-tile 16/WG (1024 WGs = 4 WG/CU), V-frag
// loads hoisted before exp/LDS-write (barrier drain completes them "for free"),
// K-frags prefetched one iteration ahead into registers. Structure/sync
// identical to R7's verified kFA. All other kernels unchanged.
// Stages: k0w -> k0_tt -> k2 qkv -> k3 params -> kFA attn+tmax -> k5 -> k6.

typedef __attribute__((ext_vector_type(8))) short short8;
typedef __attribute__((ext_vector_type(4))) short short4v;
typedef __attribute__((ext_vector_type(4))) float f32x4;

__device__ __forceinline__ unsigned short f2bf(float f){
  unsigned u = __float_as_uint(f);
  u += 0x7FFFu + ((u >> 16) & 1u);           // round-to-nearest-even
  return (unsigned short)(u >> 16);
}
// monotone float<->uint for atomicMax on floats (incl. negatives)
__device__ __forceinline__ unsigned fenc(float f){
  unsigned u = __float_as_uint(f);
  return (u & 0x80000000u) ? ~u : (u | 0x80000000u);
}
__device__ __forceinline__ float fdec(unsigned k){
  unsigned u = (k & 0x80000000u) ? (k & 0x7FFFFFFFu) : ~k;
  return __uint_as_float(u);
}

// ---------------- k0w: Wbf[384][256] bf16 (q*0.125 folded); init tmaxe/pooledEnc -
__global__ __launch_bounds__(256) void k0w(const float* __restrict__ qw,
    const float* __restrict__ kw, const float* __restrict__ vw,
    unsigned short* __restrict__ Wbf, unsigned* __restrict__ tmaxe,
    unsigned* __restrict__ pooledEnc){
  if (blockIdx.x == 0){
    const unsigned ninf = fenc(-3.0e38f);
    for (int i = threadIdx.x; i < 2048; i += 256){
      tmaxe[i] = 0u;                          // floor for encoded O-max (>=0 side)
      pooledEnc[i] = ninf;                    // true -inf floor for pooled max
    }
  }
  const int e = (blockIdx.x * 256 + threadIdx.x) * 4;   // 96 WGs * 1024 = 98304
  const int row = e >> 8, c = e & 255;
  const float* src;
  float scl = 1.0f;
  if (row < 64){ src = qw + row * 256 + c; scl = 0.125f; }
  else if (row < 128){ src = kw + (row - 64) * 256 + c; }
  else { src = vw + (row - 128) * 256 + c; }
  float4 v = *(const float4*)src;
  short4v o;
  o[0] = (short)f2bf(v.x * scl); o[1] = (short)f2bf(v.y * scl);
  o[2] = (short)f2bf(v.z * scl); o[3] = (short)f2bf(v.w * scl);
  *(short4v*)(Wbf + e) = o;
}

// ---------------- k0_tt: Tt[b][n][c] = bf16(T[b][c][n]); pooled max fold ---------
__global__ __launch_bounds__(256) void k0_tt(const float* __restrict__ T,
    unsigned short* __restrict__ Tt, unsigned* __restrict__ pooledEnc){
  const int b = blockIdx.x, nt = blockIdx.y, ct = blockIdx.z;
  const int n0 = nt * 128, c0 = ct * 32;
  const int tid = threadIdx.x;
  __shared__ float Ls[32][129];
  const int cr = tid >> 3, nq = tid & 7;      // 32 c-rows x 8 n-chunks(16 f32)
  const float* src = T + ((size_t)b * 256 + c0 + cr) * 2048 + n0 + nq * 16;
  float4 v0 = ((const float4*)src)[0];
  float4 v1 = ((const float4*)src)[1];
  float4 v2 = ((const float4*)src)[2];
  float4 v3 = ((const float4*)src)[3];
  float mx = fmaxf(fmaxf(fmaxf(v0.x, v0.y), fmaxf(v0.z, v0.w)),
                   fmaxf(fmaxf(v1.x, v1.y), fmaxf(v1.z, v1.w)));
  mx = fmaxf(mx, fmaxf(fmaxf(fmaxf(v2.x, v2.y), fmaxf(v2.z, v2.w)),
                       fmaxf(fmaxf(v3.x, v3.y), fmaxf(v3.z, v3.w))));
  mx = fmaxf(mx, __shfl_xor(mx, 1));
  mx = fmaxf(mx, __shfl_xor(mx, 2));
  mx = fmaxf(mx, __shfl_xor(mx, 4));
  if (nq == 0) atomicMax(&pooledEnc[b * 256 + c0 + cr], fenc(mx));
  float* lr = &Ls[cr][nq * 16];
  *(float4*)lr = v0; *(float4*)(lr + 4) = v1;
  *(float4*)(lr + 8) = v2; *(float4*)(lr + 12) = v3;
  __syncthreads();
  const int nr = tid >> 1, ch = tid & 1;      // 128 n-rows x 2 c-halves(16)
  unsigned short ob[16];
  #pragma unroll
  for (int j = 0; j < 16; j++) ob[j] = f2bf(Ls[ch * 16 + j][nr]);
  unsigned short* dst = Tt + ((size_t)b * 2048 + n0 + nr) * 256 + c0 + ch * 16;
  *(short8*)dst = *(short8*)&ob[0];
  *(short8*)(dst + 8) = *(short8*)&ob[8];
}

// ---------------- k2: QKV gemm, kA-shaped (no LDS, direct global frags) ----------
__global__ __launch_bounds__(256) void k2_qkv(const unsigned short* __restrict__ Wbf,
    const unsigned short* __restrict__ Tt,
    unsigned short* __restrict__ qo, unsigned short* __restrict__ ko,
    unsigned short* __restrict__ vt){
  const int wg = blockIdx.x;
  const int b = wg & 7, nt = wg >> 3;
  const int n0 = nt * 32;
  const int tid = threadIdx.x, lane = tid & 63, w = tid >> 6;
  const int l15 = lane & 15, g = lane >> 4;
  const unsigned short* Tb = Tt + (size_t)b * 2048 * 256;

  f32x4 aqk[2][2], av[4][2];
  #pragma unroll
  for (int i = 0; i < 2; i++)
    #pragma unroll
    for (int nf = 0; nf < 2; nf++) aqk[i][nf] = (f32x4){0.f,0.f,0.f,0.f};
  #pragma unroll
  for (int j = 0; j < 4; j++)
    #pragma unroll
    for (int nf = 0; nf < 2; nf++) av[j][nf] = (f32x4){0.f,0.f,0.f,0.f};

  #pragma unroll 2
  for (int kc = 0; kc < 8; kc++){
    short8 bfr[2];
    #pragma unroll
    for (int nf = 0; nf < 2; nf++)
      bfr[nf] = *(const short8*)(Tb + (size_t)(n0 + nf * 16 + l15) * 256 + kc * 32 + g * 8);
    short8 aq[2];
    #pragma unroll
    for (int i = 0; i < 2; i++)
      aq[i] = *(const short8*)(Wbf + (size_t)((2 * w + i) * 16 + l15) * 256 + kc * 32 + g * 8);
    short8 afv[4];
    #pragma unroll
    for (int j = 0; j < 4; j++)
      afv[j] = *(const short8*)(Wbf + (size_t)(128 + (4 * w + j) * 16 + l15) * 256 + kc * 32 + g * 8);
    #pragma unroll
    for (int i = 0; i < 2; i++)
      #pragma unroll
      for (int nf = 0; nf < 2; nf++)
        aqk[i][nf] = __builtin_amdgcn_mfma_f32_16x16x32_bf16(aq[i], bfr[nf], aqk[i][nf], 0, 0, 0);
    #pragma unroll
    for (int j = 0; j < 4; j++)
      #pragma unroll
      for (int nf = 0; nf < 2; nf++)
        av[j][nf] = __builtin_amdgcn_mfma_f32_16x16x32_bf16(bfr[nf], afv[j], av[j][nf], 0, 0, 0);
  }
  unsigned short* qk = (w < 2) ? qo : ko;
  #pragma unroll
  for (int i = 0; i < 2; i++)
    #pragma unroll
    for (int nf = 0; nf < 2; nf++){
      int n = n0 + nf * 16 + l15;
      int cbase = (w & 1) * 32 + i * 16 + g * 4;
      short4v pk;
      #pragma unroll
      for (int r = 0; r < 4; r++) pk[r] = (short)f2bf(aqk[i][nf][r]);
      *(short4v*)(qk + ((size_t)b * 2048 + n) * 64 + cbase) = pk;
    }
  #pragma unroll
  for (int j = 0; j < 4; j++)
    #pragma unroll
    for (int nf = 0; nf < 2; nf++){
      int o = (4 * w + j) * 16 + l15;
      int nb2 = n0 + nf * 16 + g * 4;
      short4v pv;
      #pragma unroll
      for (int r = 0; r < 4; r++) pv[r] = (short)f2bf(av[j][nf][r]);
      *(short4v*)(vt + ((size_t)b * 256 + o) * 2048 + nb2) = pv;
    }
}

// ---------------- K3: params[b][r] = pooled[b] . ctrl_w[r] + ctrl_b[r] -----------
__global__ __launch_bounds__(256) void k3_params(const unsigned* __restrict__ pooledEnc,
    const float* __restrict__ cw, const float* __restrict__ cb,
    float* __restrict__ params){
  __shared__ float P[8 * 256];
  const int tid = threadIdx.x;
  for (int i = tid; i < 2048; i += 256) P[i] = fdec(pooledEnc[i]);
  __syncthreads();
  const int w = tid >> 6, lane = tid & 63;
  const int r = blockIdx.x * 4 + w;
  if (r >= 8385) return;
  float4 c4 = ((const float4*)(cw + (size_t)r * 256))[lane];
  float bias = cb[r];
  #pragma unroll
  for (int b = 0; b < 8; b++){
    const float* pbp = P + b * 256 + lane * 4;
    float s = c4.x * pbp[0] + c4.y * pbp[1] + c4.z * pbp[2] + c4.w * pbp[3];
    #pragma unroll
    for (int d = 1; d < 64; d <<= 1) s += __shfl_xor(s, d);
    if (lane == 0) params[b * 8385 + r] = s + bias;
  }
}

// ---------------- kFA v2: fused attention, 16-q tiles, hoisted loads -------------
// 1024 WGs (b = wg&7 XCD-local, qt = wg>>3 -> 16 q-rows), 4 waves, 4 WG/CU.
// Per 64-m chunk: issue V frags early; QK with prefetched K; prefetch K(t+1);
// exp -> swizzled LDS P tile [16 q][64 m] (dbuf, 1 barrier); PV: wave w owns
// o-quarter, af from LDS, bf = the hoisted V frags. Denominators in regs.
__global__ __launch_bounds__(256, 4) void kFA(
    const unsigned short* __restrict__ Qg, const unsigned short* __restrict__ Kg,
    const unsigned short* __restrict__ Vt, unsigned* __restrict__ tmaxe){
  const int wg = blockIdx.x;
  const int b = wg & 7, qt = wg >> 3;
  const int q0 = qt * 16;
  const int tid = threadIdx.x, lane = tid & 63, w = tid >> 6;
  const int l15 = lane & 15, g = lane >> 4;
  __shared__ __align__(16) unsigned char Plds[2][2048];  // P dbuf: [16 q][128 B]
  __shared__ float wsum[16][4];
  __shared__ float sden[16];

  const unsigned short* Qb = Qg + (size_t)b * 2048 * 64;
  const unsigned short* Kb = Kg + (size_t)b * 2048 * 64;
  const unsigned short* Vb = Vt + (size_t)b * 256 * 2048;

  short8 qf[2];
  #pragma unroll
  for (int kc = 0; kc < 2; kc++)
    qf[kc] = *(const short8*)(Qb + (size_t)(q0 + l15) * 64 + kc * 32 + g * 8);

  float ps[4] = {0.f, 0.f, 0.f, 0.f};
  f32x4 acc[4];
  #pragma unroll
  for (int oi = 0; oi < 4; oi++) acc[oi] = (f32x4){0.f,0.f,0.f,0.f};

  // K prefetch for t=0 (this wave's m-slice [w*16, +16))
  short8 kf[2];
  #pragma unroll
  for (int kc = 0; kc < 2; kc++)
    kf[kc] = *(const short8*)(Kb + (size_t)(w * 16 + l15) * 64 + kc * 32 + g * 8);

  for (int t = 0; t < 32; ++t){
    const int mb = t * 64;
    unsigned char* Pl = Plds[t & 1];
    // 1. issue V frags for this chunk early (no LDS dependency)
    short8 vf[4][2];
    #pragma unroll
    for (int oi = 0; oi < 4; oi++)
      #pragma unroll
      for (int kc = 0; kc < 2; kc++)
        vf[oi][kc] = *(const short8*)(Vb + (size_t)(w * 64 + oi * 16 + l15) * 2048 + mb + kc * 32 + g * 8);
    // 2. QK with prefetched kf: D[q = q0+g*4+r][m = mb+w*16+l15]
    f32x4 sa = (f32x4){0.f,0.f,0.f,0.f};
    #pragma unroll
    for (int kc = 0; kc < 2; kc++)
      sa = __builtin_amdgcn_mfma_f32_16x16x32_bf16(qf[kc], kf[kc], sa, 0, 0, 0);
    // 3. prefetch K for t+1 (lands during exp/pack/barrier)
    if (t < 31){
      #pragma unroll
      for (int kc = 0; kc < 2; kc++)
        kf[kc] = *(const short8*)(Kb + (size_t)(mb + 64 + w * 16 + l15) * 64 + kc * 32 + g * 8);
    }
    // 4. exp + swizzled LDS write; accumulate row-sum partials
    #pragma unroll
    for (int r = 0; r < 4; r++){
      float p = __expf(sa[r]);
      ps[r] += p;
      int row = g * 4 + r;
      int col = w * 16 + l15;
      *(unsigned short*)(Pl + ((unsigned)(row * 128 + col * 2) ^ ((unsigned)(row & 7) << 4))) = f2bf(p);
    }
    __syncthreads();                                     // P ready; vf/kf drained
    // 5. PV: wave w owns o-quarter [w*64, +64), all 16 q
    short8 af[2];
    #pragma unroll
    for (int kc = 0; kc < 2; kc++)
      af[kc] = *(const short8*)(Pl + (((unsigned)(l15 * 128 + kc * 64 + g * 16)) ^ ((unsigned)(l15 & 7) << 4)));
    #pragma unroll
    for (int oi = 0; oi < 4; oi++)
      #pragma unroll
      for (int kc = 0; kc < 2; kc++)
        acc[oi] = __builtin_amdgcn_mfma_f32_16x16x32_bf16(af[kc], vf[oi][kc], acc[oi], 0, 0, 0);
  }
  // denominators: reduce in-lane partials over l15 group, then across waves
  #pragma unroll
  for (int r = 0; r < 4; r++){
    float s = ps[r];
    s += __shfl_xor(s, 1); s += __shfl_xor(s, 2);
    s += __shfl_xor(s, 4); s += __shfl_xor(s, 8);
    if (l15 == 0) wsum[g * 4 + r][w] = s;
  }
  __syncthreads();
  if (tid < 16) sden[tid] = wsum[tid][0] + wsum[tid][1] + wsum[tid][2] + wsum[tid][3];
  __syncthreads();
  float inv[4];
  #pragma unroll
  for (int r = 0; r < 4; r++) inv[r] = 1.0f / sden[g * 4 + r];
  #pragma unroll
  for (int oi = 0; oi < 4; oi++){
    float cm = -1e30f;
    #pragma unroll
    for (int r = 0; r < 4; r++)
      cm = fmaxf(cm, acc[oi][r] * inv[r]);                // max over q rows g*4+r
    cm = fmaxf(cm, __shfl_xor(cm, 16));
    cm = fmaxf(cm, __shfl_xor(cm, 32));                   // max over all 16 q
    if (lane < 16)
      atomicMax(&tmaxe[b * 256 + w * 64 + oi * 16 + l15], fenc(cm));
  }
}

// ---------------- K5: W_eff = P0 + P1*t + P2 (bf16); bias_eff; w0/w1 -> bf16 -----
__global__ __launch_bounds__(256) void k5_weff(const float* __restrict__ proj_w,
    const float* __restrict__ proj_b, const unsigned* __restrict__ tmaxe,
    const float* __restrict__ params, unsigned short* __restrict__ weff,
    float* __restrict__ beff, unsigned short* __restrict__ w0b,
    unsigned short* __restrict__ w1b){
  const int b = blockIdx.y, o = blockIdx.x;
  const int c = threadIdx.x;                  // 256
  float t = fdec(tmaxe[b * 256 + c]);
  float p0 = proj_w[o * 768 + c];
  float p1 = proj_w[o * 768 + 256 + c];
  float p2 = proj_w[o * 768 + 512 + c];
  weff[((size_t)b * 64 + o) * 256 + c] = f2bf(p0 + p1 * t + p2);
  float s = p0 * t;
  #pragma unroll
  for (int d = 1; d < 64; d <<= 1) s += __shfl_xor(s, d);
  __shared__ float sm[4];
  if ((c & 63) == 0) sm[c >> 6] = s;
  __syncthreads();
  if (c == 0) beff[b * 64 + o] = proj_b[o] - (sm[0] + sm[1] + sm[2] + sm[3]);
  if (c < 64)        w0b[((size_t)b * 64 + o) * 64 + c] = f2bf(params[b * 8385 + o * 64 + c]);
  else if (c < 128)  w1b[((size_t)b * 64 + o) * 64 + (c - 64)] = f2bf(params[b * 8385 + 4096 + o * 64 + (c - 64)]);
}

// ---------------- K6: fused scene pipeline (scene read exactly once) -------------
__global__ __launch_bounds__(512) void k6_main(const float* __restrict__ Sg,
    const unsigned short* __restrict__ weff, const float* __restrict__ beff,
    const unsigned short* __restrict__ w0b, const unsigned short* __restrict__ w1b,
    const float* __restrict__ params, float* __restrict__ out){
  const int b = blockIdx.y, nt = blockIdx.x;
  const int n0 = nt * 256;
  const int tid = threadIdx.x, lane = tid & 63, w = tid >> 6;
  const int l15 = lane & 15, g = lane >> 4;
  __shared__ __align__(16) unsigned char smem[65536];
  unsigned short* H0 = (unsigned short*)smem;            // [n][64] XOR-swizzled, 32 KB
  unsigned char*  Ub = smem + 32768;                     // Bs32 (16KB) then H1 (32KB)
  unsigned short* H1 = (unsigned short*)Ub;

  const float* Sb = Sg + (size_t)b * 256 * 16384;
  const unsigned short* We = weff + (size_t)b * 64 * 256;
  f32x4 a0[4][2];
  #pragma unroll
  for (int mi = 0; mi < 4; mi++)
    #pragma unroll
    for (int ni = 0; ni < 2; ni++) a0[mi][ni] = (f32x4){0.f,0.f,0.f,0.f};

  const int scc = tid & 31;                   // c row within k-tile
  const int snb = (tid >> 5) * 16;            // 16 n per thread
  for (int k0 = 0; k0 < 256; k0 += 32){
    const float* src = Sb + (size_t)(k0 + scc) * 16384 + n0 + snb;
    float4 v0 = ((const float4*)src)[0];
    float4 v1 = ((const float4*)src)[1];
    float4 v2 = ((const float4*)src)[2];
    float4 v3 = ((const float4*)src)[3];
    float vals[16] = {v0.x,v0.y,v0.z,v0.w, v1.x,v1.y,v1.z,v1.w,
                      v2.x,v2.y,v2.z,v2.w, v3.x,v3.y,v3.z,v3.w};
    #pragma unroll
    for (int j = 0; j < 16; j++){
      int n = snb + j;
      unsigned byteo = ((unsigned)(n * 64 + scc * 2)) ^ ((unsigned)((n >> 1) & 3) << 4);
      *(unsigned short*)(Ub + byteo) = f2bf(vals[j]);
    }
    __syncthreads();
    short8 bf0[2];
    #pragma unroll
    for (int ni = 0; ni < 2; ni++){
      int n = w * 32 + ni * 16 + l15;
      bf0[ni] = *(const short8*)(Ub + (((unsigned)(n * 64 + g * 16)) ^ ((unsigned)((n >> 1) & 3) << 4)));
    }
    #pragma unroll
    for (int mi = 0; mi < 4; mi++){
      short8 af = *(const short8*)(We + (mi * 16 + l15) * 256 + k0 + g * 8);
      #pragma unroll
      for (int ni = 0; ni < 2; ni++)
        a0[mi][ni] = __builtin_amdgcn_mfma_f32_16x16x32_bf16(af, bf0[ni], a0[mi][ni], 0, 0, 0);
    }
    __syncthreads();
  }
  const float* be = beff + b * 64;
  #pragma unroll
  for (int mi = 0; mi < 4; mi++)
    #pragma unroll
    for (int ni = 0; ni < 2; ni++){
      int n = w * 32 + ni * 16 + l15;
      unsigned base = ((unsigned)(n * 128 + mi * 32 + g * 8)) ^ ((unsigned)((n & 7) << 4));
      unsigned short hh[4];
      #pragma unroll
      for (int r = 0; r < 4; r++){
        int o = mi * 16 + g * 4 + r;
        hh[r] = f2bf(fmaxf(a0[mi][ni][r] + be[o], 0.f));
      }
      *(unsigned*)((unsigned char*)H0 + base)     = (unsigned)hh[0] | ((unsigned)hh[1] << 16);
      *(unsigned*)((unsigned char*)H0 + base + 4) = (unsigned)hh[2] | ((unsigned)hh[3] << 16);
    }
  __syncthreads();
  f32x4 a1[4][2];
  #pragma unroll
  for (int mi = 0; mi < 4; mi++)
    #pragma unroll
    for (int ni = 0; ni < 2; ni++) a1[mi][ni] = (f32x4){0.f,0.f,0.f,0.f};
  const unsigned short* W0 = w0b + (size_t)b * 4096;
  #pragma unroll
  for (int ks = 0; ks < 2; ks++){
    short8 bfh[2];
    #pragma unroll
    for (int ni = 0; ni < 2; ni++){
      int n = w * 32 + ni * 16 + l15;
      unsigned off = ((unsigned)(n * 128 + ks * 64 + g * 16)) ^ ((unsigned)((n & 7) << 4));
      bfh[ni] = *(const short8*)((unsigned char*)H0 + off);
    }
    #pragma unroll
    for (int mi = 0; mi < 4; mi++){
      short8 af = *(const short8*)(W0 + (mi * 16 + l15) * 64 + ks * 32 + g * 8);
      #pragma unroll
      for (int ni = 0; ni < 2; ni++)
        a1[mi][ni] = __builtin_amdgcn_mfma_f32_16x16x32_bf16(af, bfh[ni], a1[mi][ni], 0, 0, 0);
    }
  }
  const float* pp = params + (size_t)b * 8385;
  const float* b0p = pp + 8256;
  #pragma unroll
  for (int mi = 0; mi < 4; mi++)
    #pragma unroll
    for (int ni = 0; ni < 2; ni++){
      int n = w * 32 + ni * 16 + l15;
      unsigned base = ((unsigned)(n * 128 + mi * 32 + g * 8)) ^ ((unsigned)((n & 7) << 4));
      unsigned short hh[4];
      #pragma unroll
      for (int r = 0; r < 4; r++){
        int o = mi * 16 + g * 4 + r;
        hh[r] = f2bf(fmaxf(a1[mi][ni][r] + b0p[o], 0.f));
      }
      *(unsigned*)((unsigned char*)H1 + base)     = (unsigned)hh[0] | ((unsigned)hh[1] << 16);
      *(unsigned*)((unsigned char*)H1 + base + 4) = (unsigned)hh[2] | ((unsigned)hh[3] << 16);
    }
  __syncthreads();
  f32x4 a2[4][2];
  #pragma unroll
  for (int mi = 0; mi < 4; mi++)
    #pragma unroll
    for (int ni = 0; ni < 2; ni++) a2[mi][ni] = (f32x4){0.f,0.f,0.f,0.f};
  const unsigned short* W1 = w1b + (size_t)b * 4096;
  #pragma unroll
  for (int ks = 0; ks < 2; ks++){
    short8 bfh[2];
    #pragma unroll
    for (int ni = 0; ni < 2; ni++){
      int n = w * 32 + ni * 16 + l15;
      unsigned off = ((unsigned)(n * 128 + ks * 64 + g * 16)) ^ ((unsigned)((n & 7) << 4));
      bfh[ni] = *(const short8*)((unsigned char*)H1 + off);
    }
    #pragma unroll
    for (int mi = 0; mi < 4; mi++){
      short8 af = *(const short8*)(W1 + (mi * 16 + l15) * 64 + ks * 32 + g * 8);
      #pragma unroll
      for (int ni = 0; ni < 2; ni++)
        a2[mi][ni] = __builtin_amdgcn_mfma_f32_16x16x32_bf16(af, bfh[ni], a2[mi][ni], 0, 0, 0);
    }
  }
  const float* b1p = pp + 8320;
  const float* w2p = pp + 8192;
  float b2v = pp[8384];
  #pragma unroll
  for (int ni = 0; ni < 2; ni++){
    float t = 0.f;
    #pragma unroll
    for (int mi = 0; mi < 4; mi++)
      #pragma unroll
      for (int r = 0; r < 4; r++){
        int o = mi * 16 + g * 4 + r;
        t += w2p[o] * fmaxf(a2[mi][ni][r] + b1p[o], 0.f);
      }
    t += __shfl_xor(t, 16);
    t += __shfl_xor(t, 32);
    if (lane < 16)
      out[(size_t)b * 16384 + n0 + w * 32 + ni * 16 + l15] = t + b2v;
  }
}

extern "C" void kernel_launch(void* const* d_in, const int* in_sizes, int n_in,
                              void* d_out, int out_size, void* d_ws, size_t ws_size,
                              hipStream_t stream){
  const float* scene = (const float*)d_in[0];
  const float* tmpl  = (const float*)d_in[1];
  const float* qw    = (const float*)d_in[2];
  const float* kw    = (const float*)d_in[3];
  const float* vw    = (const float*)d_in[4];
  const float* pw    = (const float*)d_in[5];
  const float* pb    = (const float*)d_in[6];
  const float* cw    = (const float*)d_in[7];
  const float* cb    = (const float*)d_in[8];
  float* out = (float*)d_out;
  char* ws = (char*)d_ws;

  unsigned short* Q      = (unsigned short*)(ws + 0);                    // 2 MB
  unsigned short* K      = (unsigned short*)(ws + (2u << 20));           // 2 MB
  unsigned short* V      = (unsigned short*)(ws + (4u << 20));           // 8 MB
  unsigned*       pooledEnc = (unsigned*)(ws + (12u << 20));             // 8 KB
  unsigned*       tmaxe  = (unsigned*)(ws + (12u << 20) + 8192);         // 8 KB
  float*          params = (float*)(ws + (12u << 20) + 16384);           // 268 KB
  unsigned short* w0b    = (unsigned short*)(ws + (13u << 20));          // 64 KB
  unsigned short* w1b    = (unsigned short*)(ws + (13u << 20) + 65536);  // 64 KB
  unsigned short* weff   = (unsigned short*)(ws + (13u << 20) + 131072); // 256 KB
  float*          beff   = (float*)(ws + (13u << 20) + 131072 + 262144); // 2 KB
  unsigned short* Wbf    = (unsigned short*)(ws + (14u << 20) + 131072); // 192 KB
  unsigned short* Tt     = (unsigned short*)(ws + (16u << 20));          // 8 MB

  k0w<<<dim3(96), dim3(256), 0, stream>>>(qw, kw, vw, Wbf, tmaxe, pooledEnc);
  k0_tt<<<dim3(8, 16, 8), dim3(256), 0, stream>>>(tmpl, Tt, pooledEnc);
  k2_qkv<<<dim3(512), dim3(256), 0, stream>>>(Wbf, Tt, Q, K, V);
  k3_params<<<dim3(2097), dim3(256), 0, stream>>>(pooledEnc, cw, cb, params);
  kFA<<<dim3(1024), dim3(256), 0, stream>>>(Q, K, V, tmaxe);
  k5_weff<<<dim3(64, 8), dim3(256), 0, stream>>>(pw, pb, tmaxe, params, weff, beff, w0b, w1b);
  k6_main<<<dim3(64, 8), dim3(512), 0, stream>>>(scene, weff, beff, w0b, w1b, params, out);
}

// Round 9
// 153.027 us; speedup vs baseline: 1.5195x; 1.5195x over previous
//
#include <hip/hip_runtime.h>

// DynamicConvolution fused pipeline for MI355X (gfx950).
// R9: revert to R6's split kA/kB (best-known attention) and fix their measured
// occupancy defect: kA -> 512 thr x 512 WGs (16 waves/CU), kB -> o-split into
// halves (512 WGs x 256 thr, 2 WG/CU). Per-wave inner code unchanged from the
// proven R6 kernels. Fused-flash direction abandoned (R7/R8: V-reuse traffic
// x scattered frag loads dominate).
// Stages: k0w -> k0_tt -> k2 qkv -> k3 params -> kA exp(QK^T) -> kB PV+tmax ->
//         k5 W_eff -> k6 fused scene MLP.

typedef __attribute__((ext_vector_type(8))) short short8;
typedef __attribute__((ext_vector_type(4))) short short4v;
typedef __attribute__((ext_vector_type(4))) float f32x4;

__device__ __forceinline__ unsigned short f2bf(float f){
  unsigned u = __float_as_uint(f);
  u += 0x7FFFu + ((u >> 16) & 1u);           // round-to-nearest-even
  return (unsigned short)(u >> 16);
}
// monotone float<->uint for atomicMax on floats (incl. negatives)
__device__ __forceinline__ unsigned fenc(float f){
  unsigned u = __float_as_uint(f);
  return (u & 0x80000000u) ? ~u : (u | 0x80000000u);
}
__device__ __forceinline__ float fdec(unsigned k){
  unsigned u = (k & 0x80000000u) ? (k & 0x7FFFFFFFu) : ~k;
  return __uint_as_float(u);
}

// ---------------- k0w: Wbf[384][256] bf16 (q*0.125 folded); init tmaxe/pooledEnc -
__global__ __launch_bounds__(256) void k0w(const float* __restrict__ qw,
    const float* __restrict__ kw, const float* __restrict__ vw,
    unsigned short* __restrict__ Wbf, unsigned* __restrict__ tmaxe,
    unsigned* __restrict__ pooledEnc){
  if (blockIdx.x == 0){
    const unsigned ninf = fenc(-3.0e38f);
    for (int i = threadIdx.x; i < 2048; i += 256){
      tmaxe[i] = 0u;                          // floor for encoded O-max (>=0 side)
      pooledEnc[i] = ninf;                    // true -inf floor for pooled max
    }
  }
  const int e = (blockIdx.x * 256 + threadIdx.x) * 4;   // 96 WGs * 1024 = 98304
  const int row = e >> 8, c = e & 255;
  const float* src;
  float scl = 1.0f;
  if (row < 64){ src = qw + row * 256 + c; scl = 0.125f; }
  else if (row < 128){ src = kw + (row - 64) * 256 + c; }
  else { src = vw + (row - 128) * 256 + c; }
  float4 v = *(const float4*)src;
  short4v o;
  o[0] = (short)f2bf(v.x * scl); o[1] = (short)f2bf(v.y * scl);
  o[2] = (short)f2bf(v.z * scl); o[3] = (short)f2bf(v.w * scl);
  *(short4v*)(Wbf + e) = o;
}

// ---------------- k0_tt: Tt[b][n][c] = bf16(T[b][c][n]); pooled max fold ---------
__global__ __launch_bounds__(256) void k0_tt(const float* __restrict__ T,
    unsigned short* __restrict__ Tt, unsigned* __restrict__ pooledEnc){
  const int b = blockIdx.x, nt = blockIdx.y, ct = blockIdx.z;
  const int n0 = nt * 128, c0 = ct * 32;
  const int tid = threadIdx.x;
  __shared__ float Ls[32][129];
  const int cr = tid >> 3, nq = tid & 7;      // 32 c-rows x 8 n-chunks(16 f32)
  const float* src = T + ((size_t)b * 256 + c0 + cr) * 2048 + n0 + nq * 16;
  float4 v0 = ((const float4*)src)[0];
  float4 v1 = ((const float4*)src)[1];
  float4 v2 = ((const float4*)src)[2];
  float4 v3 = ((const float4*)src)[3];
  float mx = fmaxf(fmaxf(fmaxf(v0.x, v0.y), fmaxf(v0.z, v0.w)),
                   fmaxf(fmaxf(v1.x, v1.y), fmaxf(v1.z, v1.w)));
  mx = fmaxf(mx, fmaxf(fmaxf(fmaxf(v2.x, v2.y), fmaxf(v2.z, v2.w)),
                       fmaxf(fmaxf(v3.x, v3.y), fmaxf(v3.z, v3.w))));
  mx = fmaxf(mx, __shfl_xor(mx, 1));
  mx = fmaxf(mx, __shfl_xor(mx, 2));
  mx = fmaxf(mx, __shfl_xor(mx, 4));
  if (nq == 0) atomicMax(&pooledEnc[b * 256 + c0 + cr], fenc(mx));
  float* lr = &Ls[cr][nq * 16];
  *(float4*)lr = v0; *(float4*)(lr + 4) = v1;
  *(float4*)(lr + 8) = v2; *(float4*)(lr + 12) = v3;
  __syncthreads();
  const int nr = tid >> 1, ch = tid & 1;      // 128 n-rows x 2 c-halves(16)
  unsigned short ob[16];
  #pragma unroll
  for (int j = 0; j < 16; j++) ob[j] = f2bf(Ls[ch * 16 + j][nr]);
  unsigned short* dst = Tt + ((size_t)b * 2048 + n0 + nr) * 256 + c0 + ch * 16;
  *(short8*)dst = *(short8*)&ob[0];
  *(short8*)(dst + 8) = *(short8*)&ob[8];
}

// ---------------- k2: QKV gemm, kA-shaped (no LDS, direct global frags) ----------
__global__ __launch_bounds__(256) void k2_qkv(const unsigned short* __restrict__ Wbf,
    const unsigned short* __restrict__ Tt,
    unsigned short* __restrict__ qo, unsigned short* __restrict__ ko,
    unsigned short* __restrict__ vt){
  const int wg = blockIdx.x;
  const int b = wg & 7, nt = wg >> 3;
  const int n0 = nt * 32;
  const int tid = threadIdx.x, lane = tid & 63, w = tid >> 6;
  const int l15 = lane & 15, g = lane >> 4;
  const unsigned short* Tb = Tt + (size_t)b * 2048 * 256;

  f32x4 aqk[2][2], av[4][2];
  #pragma unroll
  for (int i = 0; i < 2; i++)
    #pragma unroll
    for (int nf = 0; nf < 2; nf++) aqk[i][nf] = (f32x4){0.f,0.f,0.f,0.f};
  #pragma unroll
  for (int j = 0; j < 4; j++)
    #pragma unroll
    for (int nf = 0; nf < 2; nf++) av[j][nf] = (f32x4){0.f,0.f,0.f,0.f};

  #pragma unroll 2
  for (int kc = 0; kc < 8; kc++){
    short8 bfr[2];
    #pragma unroll
    for (int nf = 0; nf < 2; nf++)
      bfr[nf] = *(const short8*)(Tb + (size_t)(n0 + nf * 16 + l15) * 256 + kc * 32 + g * 8);
    short8 aq[2];
    #pragma unroll
    for (int i = 0; i < 2; i++)
      aq[i] = *(const short8*)(Wbf + (size_t)((2 * w + i) * 16 + l15) * 256 + kc * 32 + g * 8);
    short8 afv[4];
    #pragma unroll
    for (int j = 0; j < 4; j++)
      afv[j] = *(const short8*)(Wbf + (size_t)(128 + (4 * w + j) * 16 + l15) * 256 + kc * 32 + g * 8);
    #pragma unroll
    for (int i = 0; i < 2; i++)
      #pragma unroll
      for (int nf = 0; nf < 2; nf++)
        aqk[i][nf] = __builtin_amdgcn_mfma_f32_16x16x32_bf16(aq[i], bfr[nf], aqk[i][nf], 0, 0, 0);
    #pragma unroll
    for (int j = 0; j < 4; j++)
      #pragma unroll
      for (int nf = 0; nf < 2; nf++)
        av[j][nf] = __builtin_amdgcn_mfma_f32_16x16x32_bf16(bfr[nf], afv[j], av[j][nf], 0, 0, 0);
  }
  unsigned short* qk = (w < 2) ? qo : ko;
  #pragma unroll
  for (int i = 0; i < 2; i++)
    #pragma unroll
    for (int nf = 0; nf < 2; nf++){
      int n = n0 + nf * 16 + l15;
      int cbase = (w & 1) * 32 + i * 16 + g * 4;
      short4v pk;
      #pragma unroll
      for (int r = 0; r < 4; r++) pk[r] = (short)f2bf(aqk[i][nf][r]);
      *(short4v*)(qk + ((size_t)b * 2048 + n) * 64 + cbase) = pk;
    }
  #pragma unroll
  for (int j = 0; j < 4; j++)
    #pragma unroll
    for (int nf = 0; nf < 2; nf++){
      int o = (4 * w + j) * 16 + l15;
      int nb2 = n0 + nf * 16 + g * 4;
      short4v pv;
      #pragma unroll
      for (int r = 0; r < 4; r++) pv[r] = (short)f2bf(av[j][nf][r]);
      *(short4v*)(vt + ((size_t)b * 256 + o) * 2048 + nb2) = pv;
    }
}

// ---------------- K3: params[b][r] = pooled[b] . ctrl_w[r] + ctrl_b[r] -----------
__global__ __launch_bounds__(256) void k3_params(const unsigned* __restrict__ pooledEnc,
    const float* __restrict__ cw, const float* __restrict__ cb,
    float* __restrict__ params){
  __shared__ float P[8 * 256];
  const int tid = threadIdx.x;
  for (int i = tid; i < 2048; i += 256) P[i] = fdec(pooledEnc[i]);
  __syncthreads();
  const int w = tid >> 6, lane = tid & 63;
  const int r = blockIdx.x * 4 + w;
  if (r >= 8385) return;
  float4 c4 = ((const float4*)(cw + (size_t)r * 256))[lane];
  float bias = cb[r];
  #pragma unroll
  for (int b = 0; b < 8; b++){
    const float* pbp = P + b * 256 + lane * 4;
    float s = c4.x * pbp[0] + c4.y * pbp[1] + c4.z * pbp[2] + c4.w * pbp[3];
    #pragma unroll
    for (int d = 1; d < 64; d <<= 1) s += __shfl_xor(s, d);
    if (lane == 0) params[b * 8385 + r] = s + bias;
  }
}

// ---------------- kA v2: P (tiled) = exp(S); 512 thr, q-tile 32, 16 waves/CU -----
// grid 64*nb WGs (b = wg&bmask XCD-local, qt = wg>>bshift -> 32 q-rows).
// 8 waves: wave w owns m-chunk [w*256, +256) in 4 subtiles of 64.
// P layout: tiles [qb(128)][mb(128)][lane(64)][r(4)] (R6-proven); one coalesced
// short4v store per (qi,mi) tile. Per-wave inner code identical to R6 kA.
__global__ __launch_bounds__(512, 4) void kA_scores(
    const unsigned short* __restrict__ Qg, const unsigned short* __restrict__ Kg,
    unsigned short* __restrict__ Pg, float* __restrict__ sbuf,
    int b0, int bshift){
  const int wg = blockIdx.x;
  const int bmask = (1 << bshift) - 1;
  const int b = b0 + (wg & bmask);
  const int q0 = (wg >> bshift) * 32;
  const int qb0 = (wg >> bshift) * 2;
  const int tid = threadIdx.x, lane = tid & 63, w = tid >> 6;
  const int l15 = lane & 15, g = lane >> 4;
  __shared__ float wsum[32][8];
  const unsigned short* Qb = Qg + (size_t)b * 2048 * 64;
  const unsigned short* Kb = Kg + (size_t)b * 2048 * 64;
  unsigned short* Pb = Pg + (size_t)(wg & bmask) * 2048 * 2048;

  short8 qf[2][2];
  #pragma unroll
  for (int qi = 0; qi < 2; qi++)
    #pragma unroll
    for (int kc = 0; kc < 2; kc++)
      qf[qi][kc] = *(const short8*)(Qb + (size_t)(q0 + qi * 16 + l15) * 64 + kc * 32 + g * 8);

  float ps[2][4];
  #pragma unroll
  for (int qi = 0; qi < 2; qi++)
    #pragma unroll
    for (int r = 0; r < 4; r++) ps[qi][r] = 0.f;

  const int wm0 = w * 256;
  for (int mt = 0; mt < 4; ++mt){
    const int mb = wm0 + mt * 64;
    short8 kf[4][2];
    #pragma unroll
    for (int mi = 0; mi < 4; mi++)
      #pragma unroll
      for (int kc = 0; kc < 2; kc++)
        kf[mi][kc] = *(const short8*)(Kb + (size_t)(mb + mi * 16 + l15) * 64 + kc * 32 + g * 8);
    #pragma unroll
    for (int qi = 0; qi < 2; qi++){
      f32x4 sa[4];
      #pragma unroll
      for (int mi = 0; mi < 4; mi++) sa[mi] = (f32x4){0.f,0.f,0.f,0.f};
      #pragma unroll
      for (int mi = 0; mi < 4; mi++)
        #pragma unroll
        for (int kc = 0; kc < 2; kc++)
          sa[mi] = __builtin_amdgcn_mfma_f32_16x16x32_bf16(qf[qi][kc], kf[mi][kc], sa[mi], 0, 0, 0);
      #pragma unroll
      for (int mi = 0; mi < 4; mi++){
        short4v pk;
        #pragma unroll
        for (int r = 0; r < 4; r++){
          float p = __expf(sa[mi][r]);
          ps[qi][r] += p;
          pk[r] = (short)f2bf(p);
        }
        *(short4v*)(Pb + ((size_t)((qb0 + qi) * 128 + w * 16 + mt * 4 + mi)) * 256 + lane * 4) = pk;
      }
    }
  }
  #pragma unroll
  for (int qi = 0; qi < 2; qi++)
    #pragma unroll
    for (int r = 0; r < 4; r++){
      float t = ps[qi][r];
      t += __shfl_xor(t, 1); t += __shfl_xor(t, 2);
      t += __shfl_xor(t, 4); t += __shfl_xor(t, 8);
      if (l15 == 0) wsum[qi * 16 + g * 4 + r][w] = t;
    }
  __syncthreads();
  if (tid < 32){
    float t = 0.f;
    #pragma unroll
    for (int i = 0; i < 8; i++) t += wsum[tid][i];
    sbuf[(size_t)b * 2048 + q0 + tid] = t;
  }
}

// ---------------- kB v2: O = P@V^T, o-split halves -> 512 WGs, 2 WG/CU -----------
// grid 64*nb (b = wg&bmask; rest = wg>>bshift: oh = rest&1 o-half, nt = rest>>1
// -> 64 n-rows). LDS: P 8KB + V-half 16KB, swizzled; staging 6x16B per thread.
// Per-wave: af[4][2] n-frags + bf[2][2] o-frags (its 32-o slice), 16 MFMA/chunk.
__global__ __launch_bounds__(256, 2) void kB_pv(
    const unsigned short* __restrict__ Pg, const unsigned short* __restrict__ Vt,
    const float* __restrict__ sbuf, unsigned* __restrict__ tmaxe,
    int b0, int bshift){
  const int wg = blockIdx.x;
  const int bmask = (1 << bshift) - 1;
  const int b = b0 + (wg & bmask);
  const int rest = wg >> bshift;
  const int oh = rest & 1;
  const int n0 = (rest >> 1) * 64;
  const int qb0 = n0 >> 4;
  const int tid = threadIdx.x, lane = tid & 63, w = tid >> 6;
  const int l15 = lane & 15, g = lane >> 4;
  __shared__ __align__(16) unsigned char smem[24576];    // Pl 8KB | Vl 16KB

  const unsigned short* Pb = Pg + (size_t)(wg & bmask) * 2048 * 2048;
  const unsigned short* Vb = Vt + ((size_t)b * 256 + oh * 128) * 2048;

  f32x4 acc[4][2];
  #pragma unroll
  for (int ni = 0; ni < 4; ni++)
    #pragma unroll
    for (int oi = 0; oi < 2; oi++) acc[ni][oi] = (f32x4){0.f,0.f,0.f,0.f};

  for (int m0 = 0; m0 < 2048; m0 += 64){
    const int mb0 = m0 >> 4;
    short8 stg[6];
    #pragma unroll
    for (int k = 0; k < 6; k++){
      int d = k * 4096 + tid * 16;
      if (k < 2){                                        // P tiles: 16 x 512B
        int ti = d >> 9;
        int qi = ti >> 2, mi = ti & 3;
        stg[k] = *(const short8*)(Pb + ((size_t)(qb0 + qi) * 128 + mb0 + mi) * 256 + ((d & 511) >> 1));
      } else {                                           // V-half rows (o-local)
        int dv = d - 8192;
        int row = dv >> 7;
        stg[k] = *(const short8*)(Vb + (size_t)row * 2048 + m0 + ((dv & 127) >> 1));
      }
    }
    __syncthreads();                                     // prev compute done reading
    #pragma unroll
    for (int k = 0; k < 6; k++){
      int d = k * 4096 + tid * 16;
      if (k < 2){
        int ti = d >> 9;
        int qi = ti >> 2, mi = ti & 3;
        int lane0 = (d & 511) >> 3;                      // even; chunk = lanes lane0, lane0+1
        #pragma unroll
        for (int idx = 0; idx < 8; idx++){
          int Lp = lane0 + (idx >> 2), r = idx & 3;
          int row = qi * 16 + ((Lp >> 4) << 2) + r;
          int col = mi * 16 + (Lp & 15);
          *(unsigned short*)(smem + ((row * 128 + col * 2) ^ ((row & 7) << 4))) =
              ((const unsigned short*)&stg[k])[idx];
        }
      } else {
        int dv = d - 8192;
        int row = dv >> 7;
        *(short8*)(smem + 8192 + (dv ^ ((row & 7) << 4))) = stg[k];
      }
    }
    __syncthreads();                                     // staging visible
    short8 af[4][2], bf[2][2];
    #pragma unroll
    for (int ni = 0; ni < 4; ni++)
      #pragma unroll
      for (int kc = 0; kc < 2; kc++){
        int row = ni * 16 + l15;
        af[ni][kc] = *(const short8*)(smem + ((row * 128 + kc * 64 + g * 16) ^ ((row & 7) << 4)));
      }
    #pragma unroll
    for (int oi = 0; oi < 2; oi++)
      #pragma unroll
      for (int kc = 0; kc < 2; kc++){
        int row = w * 32 + oi * 16 + l15;
        bf[oi][kc] = *(const short8*)(smem + 8192 + ((row * 128 + kc * 64 + g * 16) ^ ((row & 7) << 4)));
      }
    #pragma unroll
    for (int ni = 0; ni < 4; ni++)
      #pragma unroll
      for (int oi = 0; oi < 2; oi++)
        #pragma unroll
        for (int kc = 0; kc < 2; kc++)
          acc[ni][oi] = __builtin_amdgcn_mfma_f32_16x16x32_bf16(af[ni][kc], bf[oi][kc], acc[ni][oi], 0, 0, 0);
  }
  float inv[4][4];
  #pragma unroll
  for (int ni = 0; ni < 4; ni++)
    #pragma unroll
    for (int r = 0; r < 4; r++)
      inv[ni][r] = 1.0f / sbuf[(size_t)b * 2048 + n0 + ni * 16 + g * 4 + r];
  #pragma unroll
  for (int oi = 0; oi < 2; oi++){
    float cm = -1e30f;
    #pragma unroll
    for (int ni = 0; ni < 4; ni++)
      #pragma unroll
      for (int r = 0; r < 4; r++)
        cm = fmaxf(cm, acc[ni][oi][r] * inv[ni][r]);
    cm = fmaxf(cm, __shfl_xor(cm, 16));
    cm = fmaxf(cm, __shfl_xor(cm, 32));
    if (lane < 16)
      atomicMax(&tmaxe[b * 256 + oh * 128 + w * 32 + oi * 16 + lane], fenc(cm));
  }
}

// ---------------- K5: W_eff = P0 + P1*t + P2 (bf16); bias_eff; w0/w1 -> bf16 -----
__global__ __launch_bounds__(256) void k5_weff(const float* __restrict__ proj_w,
    const float* __restrict__ proj_b, const unsigned* __restrict__ tmaxe,
    const float* __restrict__ params, unsigned short* __restrict__ weff,
    float* __restrict__ beff, unsigned short* __restrict__ w0b,
    unsigned short* __restrict__ w1b){
  const int b = blockIdx.y, o = blockIdx.x;
  const int c = threadIdx.x;                  // 256
  float t = fdec(tmaxe[b * 256 + c]);
  float p0 = proj_w[o * 768 + c];
  float p1 = proj_w[o * 768 + 256 + c];
  float p2 = proj_w[o * 768 + 512 + c];
  weff[((size_t)b * 64 + o) * 256 + c] = f2bf(p0 + p1 * t + p2);
  float s = p0 * t;
  #pragma unroll
  for (int d = 1; d < 64; d <<= 1) s += __shfl_xor(s, d);
  __shared__ float sm[4];
  if ((c & 63) == 0) sm[c >> 6] = s;
  __syncthreads();
  if (c == 0) beff[b * 64 + o] = proj_b[o] - (sm[0] + sm[1] + sm[2] + sm[3]);
  if (c < 64)        w0b[((size_t)b * 64 + o) * 64 + c] = f2bf(params[b * 8385 + o * 64 + c]);
  else if (c < 128)  w1b[((size_t)b * 64 + o) * 64 + (c - 64)] = f2bf(params[b * 8385 + 4096 + o * 64 + (c - 64)]);
}

// ---------------- K6: fused scene pipeline (scene read exactly once) -------------
__global__ __launch_bounds__(512) void k6_main(const float* __restrict__ Sg,
    const unsigned short* __restrict__ weff, const float* __restrict__ beff,
    const unsigned short* __restrict__ w0b, const unsigned short* __restrict__ w1b,
    const float* __restrict__ params, float* __restrict__ out){
  const int b = blockIdx.y, nt = blockIdx.x;
  const int n0 = nt * 256;
  const int tid = threadIdx.x, lane = tid & 63, w = tid >> 6;
  const int l15 = lane & 15, g = lane >> 4;
  __shared__ __align__(16) unsigned char smem[65536];
  unsigned short* H0 = (unsigned short*)smem;            // [n][64] XOR-swizzled, 32 KB
  unsigned char*  Ub = smem + 32768;                     // Bs32 (16KB) then H1 (32KB)
  unsigned short* H1 = (unsigned short*)Ub;

  const float* Sb = Sg + (size_t)b * 256 * 16384;
  const unsigned short* We = weff + (size_t)b * 64 * 256;
  f32x4 a0[4][2];
  #pragma unroll
  for (int mi = 0; mi < 4; mi++)
    #pragma unroll
    for (int ni = 0; ni < 2; ni++) a0[mi][ni] = (f32x4){0.f,0.f,0.f,0.f};

  const int scc = tid & 31;                   // c row within k-tile
  const int snb = (tid >> 5) * 16;            // 16 n per thread
  for (int k0 = 0; k0 < 256; k0 += 32){
    const float* src = Sb + (size_t)(k0 + scc) * 16384 + n0 + snb;
    float4 v0 = ((const float4*)src)[0];
    float4 v1 = ((const float4*)src)[1];
    float4 v2 = ((const float4*)src)[2];
    float4 v3 = ((const float4*)src)[3];
    float vals[16] = {v0.x,v0.y,v0.z,v0.w, v1.x,v1.y,v1.z,v1.w,
                      v2.x,v2.y,v2.z,v2.w, v3.x,v3.y,v3.z,v3.w};
    #pragma unroll
    for (int j = 0; j < 16; j++){
      int n = snb + j;
      unsigned byteo = ((unsigned)(n * 64 + scc * 2)) ^ ((unsigned)((n >> 1) & 3) << 4);
      *(unsigned short*)(Ub + byteo) = f2bf(vals[j]);
    }
    __syncthreads();
    short8 bf0[2];
    #pragma unroll
    for (int ni = 0; ni < 2; ni++){
      int n = w * 32 + ni * 16 + l15;
      bf0[ni] = *(const short8*)(Ub + (((unsigned)(n * 64 + g * 16)) ^ ((unsigned)((n >> 1) & 3) << 4)));
    }
    #pragma unroll
    for (int mi = 0; mi < 4; mi++){
      short8 af = *(const short8*)(We + (mi * 16 + l15) * 256 + k0 + g * 8);
      #pragma unroll
      for (int ni = 0; ni < 2; ni++)
        a0[mi][ni] = __builtin_amdgcn_mfma_f32_16x16x32_bf16(af, bf0[ni], a0[mi][ni], 0, 0, 0);
    }
    __syncthreads();
  }
  const float* be = beff + b * 64;
  #pragma unroll
  for (int mi = 0; mi < 4; mi++)
    #pragma unroll
    for (int ni = 0; ni < 2; ni++){
      int n = w * 32 + ni * 16 + l15;
      unsigned base = ((unsigned)(n * 128 + mi * 32 + g * 8)) ^ ((unsigned)((n & 7) << 4));
      unsigned short hh[4];
      #pragma unroll
      for (int r = 0; r < 4; r++){
        int o = mi * 16 + g * 4 + r;
        hh[r] = f2bf(fmaxf(a0[mi][ni][r] + be[o], 0.f));
      }
      *(unsigned*)((unsigned char*)H0 + base)     = (unsigned)hh[0] | ((unsigned)hh[1] << 16);
      *(unsigned*)((unsigned char*)H0 + base + 4) = (unsigned)hh[2] | ((unsigned)hh[3] << 16);
    }
  __syncthreads();
  f32x4 a1[4][2];
  #pragma unroll
  for (int mi = 0; mi < 4; mi++)
    #pragma unroll
    for (int ni = 0; ni < 2; ni++) a1[mi][ni] = (f32x4){0.f,0.f,0.f,0.f};
  const unsigned short* W0 = w0b + (size_t)b * 4096;
  #pragma unroll
  for (int ks = 0; ks < 2; ks++){
    short8 bfh[2];
    #pragma unroll
    for (int ni = 0; ni < 2; ni++){
      int n = w * 32 + ni * 16 + l15;
      unsigned off = ((unsigned)(n * 128 + ks * 64 + g * 16)) ^ ((unsigned)((n & 7) << 4));
      bfh[ni] = *(const short8*)((unsigned char*)H0 + off);
    }
    #pragma unroll
    for (int mi = 0; mi < 4; mi++){
      short8 af = *(const short8*)(W0 + (mi * 16 + l15) * 64 + ks * 32 + g * 8);
      #pragma unroll
      for (int ni = 0; ni < 2; ni++)
        a1[mi][ni] = __builtin_amdgcn_mfma_f32_16x16x32_bf16(af, bfh[ni], a1[mi][ni], 0, 0, 0);
    }
  }
  const float* pp = params + (size_t)b * 8385;
  const float* b0p = pp + 8256;
  #pragma unroll
  for (int mi = 0; mi < 4; mi++)
    #pragma unroll
    for (int ni = 0; ni < 2; ni++){
      int n = w * 32 + ni * 16 + l15;
      unsigned base = ((unsigned)(n * 128 + mi * 32 + g * 8)) ^ ((unsigned)((n & 7) << 4));
      unsigned short hh[4];
      #pragma unroll
      for (int r = 0; r < 4; r++){
        int o = mi * 16 + g * 4 + r;
        hh[r] = f2bf(fmaxf(a1[mi][ni][r] + b0p[o], 0.f));
      }
      *(unsigned*)((unsigned char*)H1 + base)     = (unsigned)hh[0] | ((unsigned)hh[1] << 16);
      *(unsigned*)((unsigned char*)H1 + base + 4) = (unsigned)hh[2] | ((unsigned)hh[3] << 16);
    }
  __syncthreads();
  f32x4 a2[4][2];
  #pragma unroll
  for (int mi = 0; mi < 4; mi++)
    #pragma unroll
    for (int ni = 0; ni < 2; ni++) a2[mi][ni] = (f32x4){0.f,0.f,0.f,0.f};
  const unsigned short* W1 = w1b + (size_t)b * 4096;
  #pragma unroll
  for (int ks = 0; ks < 2; ks++){
    short8 bfh[2];
    #pragma unroll
    for (int ni = 0; ni < 2; ni++){
      int n = w * 32 + ni * 16 + l15;
      unsigned off = ((unsigned)(n * 128 + ks * 64 + g * 16)) ^ ((unsigned)((n & 7) << 4));
      bfh[ni] = *(const short8*)((unsigned char*)H1 + off);
    }
    #pragma unroll
    for (int mi = 0; mi < 4; mi++){
      short8 af = *(const short8*)(W1 + (mi * 16 + l15) * 64 + ks * 32 + g * 8);
      #pragma unroll
      for (int ni = 0; ni < 2; ni++)
        a2[mi][ni] = __builtin_amdgcn_mfma_f32_16x16x32_bf16(af, bfh[ni], a2[mi][ni], 0, 0, 0);
    }
  }
  const float* b1p = pp + 8320;
  const float* w2p = pp + 8192;
  float b2v = pp[8384];
  #pragma unroll
  for (int ni = 0; ni < 2; ni++){
    float t = 0.f;
    #pragma unroll
    for (int mi = 0; mi < 4; mi++)
      #pragma unroll
      for (int r = 0; r < 4; r++){
        int o = mi * 16 + g * 4 + r;
        t += w2p[o] * fmaxf(a2[mi][ni][r] + b1p[o], 0.f);
      }
    t += __shfl_xor(t, 16);
    t += __shfl_xor(t, 32);
    if (lane < 16)
      out[(size_t)b * 16384 + n0 + w * 32 + ni * 16 + l15] = t + b2v;
  }
}

extern "C" void kernel_launch(void* const* d_in, const int* in_sizes, int n_in,
                              void* d_out, int out_size, void* d_ws, size_t ws_size,
                              hipStream_t stream){
  const float* scene = (const float*)d_in[0];
  const float* tmpl  = (const float*)d_in[1];
  const float* qw    = (const float*)d_in[2];
  const float* kw    = (const float*)d_in[3];
  const float* vw    = (const float*)d_in[4];
  const float* pw    = (const float*)d_in[5];
  const float* pb    = (const float*)d_in[6];
  const float* cw    = (const float*)d_in[7];
  const float* cb    = (const float*)d_in[8];
  float* out = (float*)d_out;
  char* ws = (char*)d_ws;

  unsigned short* Q      = (unsigned short*)(ws + 0);                    // 2 MB
  unsigned short* K      = (unsigned short*)(ws + (2u << 20));           // 2 MB
  unsigned short* V      = (unsigned short*)(ws + (4u << 20));           // 8 MB
  unsigned*       pooledEnc = (unsigned*)(ws + (12u << 20));             // 8 KB
  unsigned*       tmaxe  = (unsigned*)(ws + (12u << 20) + 8192);         // 8 KB
  float*          params = (float*)(ws + (12u << 20) + 16384);           // 268 KB
  unsigned short* w0b    = (unsigned short*)(ws + (13u << 20));          // 64 KB
  unsigned short* w1b    = (unsigned short*)(ws + (13u << 20) + 65536);  // 64 KB
  unsigned short* weff   = (unsigned short*)(ws + (13u << 20) + 131072); // 256 KB
  float*          beff   = (float*)(ws + (13u << 20) + 131072 + 262144); // 2 KB
  float*          sbuf   = (float*)(ws + (14u << 20));                   // 64 KB
  unsigned short* Wbf    = (unsigned short*)(ws + (14u << 20) + 131072); // 192 KB
  unsigned short* Pbuf   = (unsigned short*)(ws + (16u << 20));          // up to 67 MB
  unsigned short* Tt     = Pbuf;   // 8 MB; dead before kA writes Pbuf (stream order)

  const size_t pPerBatch = (size_t)2048 * 2048 * 2;
  size_t avail = ws_size > (16u << 20) ? ws_size - (16u << 20) : 0;
  int nb = 8, bshift = 3;
  while (nb > 1 && (size_t)nb * pPerBatch > avail){ nb >>= 1; bshift--; }

  k0w<<<dim3(96), dim3(256), 0, stream>>>(qw, kw, vw, Wbf, tmaxe, pooledEnc);
  k0_tt<<<dim3(8, 16, 8), dim3(256), 0, stream>>>(tmpl, Tt, pooledEnc);
  k2_qkv<<<dim3(512), dim3(256), 0, stream>>>(Wbf, Tt, Q, K, V);
  k3_params<<<dim3(2097), dim3(256), 0, stream>>>(pooledEnc, cw, cb, params);
  for (int b0 = 0; b0 < 8; b0 += nb){
    kA_scores<<<dim3(64 * nb), dim3(512), 0, stream>>>(Q, K, Pbuf, sbuf, b0, bshift);
    kB_pv<<<dim3(64 * nb), dim3(256), 0, stream>>>(Pbuf, V, sbuf, tmaxe, b0, bshift);
  }
  k5_weff<<<dim3(64, 8), dim3(256), 0, stream>>>(pw, pb, tmaxe, params, weff, beff, w0b, w1b);
  k6_main<<<dim3(64, 8), dim3(512), 0, stream>>>(scene, weff, beff, w0b, w1b, params, out);
}